// Round 1
// baseline (2677.000 us; speedup 1.0000x reference)
//
#include <hip/hip_runtime.h>
#include <hip/hip_bf16.h>

// Problem constants (from reference): T=1024, B=2, E=1024, H=16, D=64, R=2*T-1
#define TT 1024
#define BB 2
#define EE 1024
#define HH 16
#define DD 64
#define RR 2047
#define TB (TT * BB)        // 2048 flattened rows of x
#define E3 (3 * EE)         // 3072

// ---------------------------------------------------------------------------
// Generic fp32 GEMM:  C[M,N] = A[M,K] @ W[N,K]^T + bias[N]
// Tiles: BM=64, BN=64, BK=16; 256 threads; 4x4 micro-tile per thread.
// ---------------------------------------------------------------------------
#define BM 64
#define BN 64
#define BK 16

__global__ __launch_bounds__(256) void gemm_bias_kernel(
    const float* __restrict__ A, const float* __restrict__ W,
    const float* __restrict__ bias, float* __restrict__ C,
    int M, int N, int K) {
  __shared__ float sA[BK][BM];
  __shared__ float sW[BK][BN];

  const int tid = threadIdx.x;
  const int n0 = blockIdx.x * BN;
  const int m0 = blockIdx.y * BM;

  const int loadK = tid & 15;   // 0..15 (k within tile)
  const int loadR = tid >> 4;   // 0..15 (row base; +16*it)

  const int tx = tid & 15;      // output col group
  const int ty = tid >> 4;      // output row group

  float acc[4][4] = {};

  for (int kk = 0; kk < K; kk += BK) {
    // stage A tile: sA[k][m] = A[(m0+m)*K + kk+k]
    #pragma unroll
    for (int it = 0; it < 4; ++it) {
      int m = loadR + 16 * it;
      int gm = m0 + m;
      sA[loadK][m] = (gm < M) ? A[(long)gm * K + kk + loadK] : 0.0f;
    }
    // stage W tile: sW[k][n] = W[(n0+n)*K + kk+k]
    #pragma unroll
    for (int it = 0; it < 4; ++it) {
      int n = loadR + 16 * it;
      int gn = n0 + n;
      sW[loadK][n] = (gn < N) ? W[(long)gn * K + kk + loadK] : 0.0f;
    }
    __syncthreads();

    #pragma unroll
    for (int k = 0; k < BK; ++k) {
      float a[4], b[4];
      #pragma unroll
      for (int i = 0; i < 4; ++i) a[i] = sA[k][ty * 4 + i];
      #pragma unroll
      for (int j = 0; j < 4; ++j) b[j] = sW[k][tx * 4 + j];
      #pragma unroll
      for (int i = 0; i < 4; ++i)
        #pragma unroll
        for (int j = 0; j < 4; ++j) acc[i][j] += a[i] * b[j];
    }
    __syncthreads();
  }

  #pragma unroll
  for (int j = 0; j < 4; ++j) {
    int gn = n0 + tx * 4 + j;
    float bv = bias[gn];
    #pragma unroll
    for (int i = 0; i < 4; ++i) {
      int gm = m0 + ty * 4 + i;
      if (gm < M) C[(long)gm * N + gn] = acc[i][j] + bv;
    }
  }
}

// ---------------------------------------------------------------------------
// Streaming relative attention with online softmax.
// One wave (64 lanes) per query row; lane d owns head-dim element d.
// score[i,j] = ((q_i + r_w) . k_j  +  (q_i + r_r) . p_{j-i+T-1}) * scale
// (rel_shift folded into the p index: shifted[i,j] = pre[i, j-i+T-1])
// ---------------------------------------------------------------------------
__global__ __launch_bounds__(256) void rel_attn_kernel(
    const float* __restrict__ qkv,   // [TB][3E], q|k|v split on last dim
    const float* __restrict__ p,     // [R][E]
    const float* __restrict__ r_w,   // [H*D]
    const float* __restrict__ r_r,   // [H*D]
    float* __restrict__ ctx) {       // [TB][E]
  const int wave = threadIdx.x >> 6;           // 0..3
  const int lane = threadIdx.x & 63;           // = d
  const int i = blockIdx.x * 4 + wave;         // query row (0..T-1)
  const int bh = blockIdx.y;                   // 0..B*H-1
  const int b = bh >> 4;
  const int h = bh & 15;

  const int hd = h * DD + lane;                // offset within E
  const long qrow = (long)(i * BB + b) * E3;

  const float qc = qkv[qrow + hd];
  const float qw = qc + r_w[hd];
  const float qr = qc + r_r[hd];

  float m = -1e30f, l = 0.0f, acc = 0.0f;
  const float scale = 0.125f;                  // 1/sqrt(64)

  for (int j = 0; j < TT; ++j) {
    const long krow = (long)(j * BB + b) * E3;
    const float kv = qkv[krow + EE + hd];
    const float pv = p[(long)(j - i + (TT - 1)) * EE + hd];
    float s = qw * kv + qr * pv;
    // 64-lane butterfly reduce
    #pragma unroll
    for (int off = 32; off > 0; off >>= 1) s += __shfl_xor(s, off, 64);
    s *= scale;

    const float mn = fmaxf(m, s);
    const float f = __expf(m - mn);
    const float w = __expf(s - mn);
    const float vv = qkv[krow + 2 * EE + hd];
    l = l * f + w;
    acc = acc * f + w * vv;
    m = mn;
  }

  ctx[(long)(i * BB + b) * EE + hd] = acc / l;
}

// ---------------------------------------------------------------------------
extern "C" void kernel_launch(void* const* d_in, const int* in_sizes, int n_in,
                              void* d_out, int out_size, void* d_ws, size_t ws_size,
                              hipStream_t stream) {
  const float* x      = (const float*)d_in[0];  // [T,B,E] -> [TB,E]
  const float* pos    = (const float*)d_in[1];  // [R,1,E] -> [R,E]
  const float* in_w   = (const float*)d_in[2];  // [3E,E]
  const float* in_b   = (const float*)d_in[3];  // [3E]
  const float* pos_w  = (const float*)d_in[4];  // [E,E]
  const float* pos_b  = (const float*)d_in[5];  // [E]
  const float* out_w  = (const float*)d_in[6];  // [E,E]
  const float* out_b  = (const float*)d_in[7];  // [E]
  const float* r_w    = (const float*)d_in[8];  // [H,D]
  const float* r_r    = (const float*)d_in[9];  // [H,D]
  float* out = (float*)d_out;                   // [TB,E]

  // workspace layout (fp32)
  float* qkv = (float*)d_ws;                    // TB * 3E
  float* pp  = qkv + (long)TB * E3;             // R * E
  float* ctx = pp + (long)RR * EE;              // TB * E

  dim3 blk(256);

  // 1) qkv = x @ in_w^T + in_b            [2048 x 3072]
  gemm_bias_kernel<<<dim3(E3 / BN, TB / BM), blk, 0, stream>>>(
      x, in_w, in_b, qkv, TB, E3, EE);

  // 2) p = pos @ pos_w^T + pos_b          [2047 x 1024]
  gemm_bias_kernel<<<dim3(EE / BN, (RR + BM - 1) / BM), blk, 0, stream>>>(
      pos, pos_w, pos_b, pp, RR, EE, EE);

  // 3) streaming relative attention -> ctx [2048 x 1024]
  rel_attn_kernel<<<dim3(TT / 4, BB * HH), blk, 0, stream>>>(
      qkv, pp, r_w, r_r, ctx);

  // 4) out = ctx @ out_w^T + out_b        [2048 x 1024]
  gemm_bias_kernel<<<dim3(EE / BN, TB / BM), blk, 0, stream>>>(
      ctx, out_w, out_b, out, TB, EE, EE);
}

// Round 2
// 725.549 us; speedup vs baseline: 3.6896x; 3.6896x over previous
//
#include <hip/hip_runtime.h>
#include <hip/hip_bf16.h>

// Problem constants: T=1024, B=2, E=1024, H=16, D=64, R=2*T-1
#define TT 1024
#define BB 2
#define EE 1024
#define HH 16
#define DD 64
#define RR 2047
#define TB (TT * TB_dummy)
#undef TB
#define TB (TT * BB)
#define E3 (3 * EE)

typedef __attribute__((ext_vector_type(4))) float f32x4;
typedef __attribute__((ext_vector_type(8))) short s16x8;

static __device__ __forceinline__ short f2bf(float x) {
  unsigned u = __builtin_bit_cast(unsigned, x);
  unsigned r = (u + 0x7FFFu + ((u >> 16) & 1u)) >> 16;
  return (short)r;
}

// ---------------------------------------------------------------------------
// fp32 GEMM:  C[M,N] = A[M,K] @ W[N,K]^T + bias[N]   (unchanged, known-good)
// ---------------------------------------------------------------------------
#define BM 64
#define BN 64
#define BK 16

__global__ __launch_bounds__(256) void gemm_bias_kernel(
    const float* __restrict__ A, const float* __restrict__ W,
    const float* __restrict__ bias, float* __restrict__ C,
    int M, int N, int K) {
  __shared__ float sA[BK][BM];
  __shared__ float sW[BK][BN];

  const int tid = threadIdx.x;
  const int n0 = blockIdx.x * BN;
  const int m0 = blockIdx.y * BM;

  const int loadK = tid & 15;
  const int loadR = tid >> 4;
  const int tx = tid & 15;
  const int ty = tid >> 4;

  float acc[4][4] = {};

  for (int kk = 0; kk < K; kk += BK) {
    #pragma unroll
    for (int it = 0; it < 4; ++it) {
      int m = loadR + 16 * it;
      int gm = m0 + m;
      sA[loadK][m] = (gm < M) ? A[(long)gm * K + kk + loadK] : 0.0f;
    }
    #pragma unroll
    for (int it = 0; it < 4; ++it) {
      int n = loadR + 16 * it;
      int gn = n0 + n;
      sW[loadK][n] = (gn < N) ? W[(long)gn * K + kk + loadK] : 0.0f;
    }
    __syncthreads();

    #pragma unroll
    for (int k = 0; k < BK; ++k) {
      float a[4], bvv[4];
      #pragma unroll
      for (int i = 0; i < 4; ++i) a[i] = sA[k][ty * 4 + i];
      #pragma unroll
      for (int j = 0; j < 4; ++j) bvv[j] = sW[k][tx * 4 + j];
      #pragma unroll
      for (int i = 0; i < 4; ++i)
        #pragma unroll
        for (int j = 0; j < 4; ++j) acc[i][j] += a[i] * bvv[j];
    }
    __syncthreads();
  }

  #pragma unroll
  for (int j = 0; j < 4; ++j) {
    int gn = n0 + tx * 4 + j;
    float bv = bias[gn];
    #pragma unroll
    for (int i = 0; i < 4; ++i) {
      int gm = m0 + ty * 4 + i;
      if (gm < M) C[(long)gm * N + gn] = acc[i][j] + bv;
    }
  }
}

// ---------------------------------------------------------------------------
// MFMA flash attention with folded relative shift.
//   block: 2 waves x 32 queries = 64 queries, one (b,h); loop over 32-key tiles
//   score[i,j] = qw_i.k_j + qr_i.p[j-i+1023]   (1/8 scale folded into qw,qr)
//   BD via Btilde = qr . pband^T (MFMA), gathered at ul = jj+31-ii through LDS
// MFMA facts used:
//   C/D: col = lane&15, row = (lane>>4)*4 + reg     [HW-verified]
//   A/B: row(col) = lane&15, k packed 8/lane-group; any consistent k-packing
//        across A and B is valid since k is summed.
// ---------------------------------------------------------------------------
#define KB 32
#define AW 2

__global__ __launch_bounds__(128) void rel_attn_mfma(
    const float* __restrict__ qkv,   // [TB][3E]
    const float* __restrict__ pp,    // [R][E]
    const float* __restrict__ rwb,   // [H*D]
    const float* __restrict__ rrb,   // [H*D]
    float* __restrict__ ctx) {       // [TB][E]
  __shared__ __align__(16) short sK[KB * 64];        // chunk-swizzled
  __shared__ __align__(16) short sPB[96 * 64];       // chunk-swizzled
  __shared__ __align__(16) short sV[KB * 65];        // odd stride (bank spread)
  __shared__ __align__(16) float sBt[AW][16 * 68];   // Btilde row-tile scratch
  __shared__ __align__(16) short sPm[AW][32 * 40];   // P round-trip

  const int tid = threadIdx.x;
  const int wv = tid >> 6;
  const int lane = tid & 63;
  const int g = lane >> 4;      // 0..3
  const int cc = lane & 15;     // 0..15
  const int i0 = blockIdx.x * 64;
  const int bh = blockIdx.y;
  const int b = bh >> 4, h = bh & 15;
  const int hoff = h * DD;
  const int base_w = 32 * (1 - wv);   // wave's band base within sPB

  // ---- Q fragments (scale folded) ----
  s16x8 qw[2][2], qr[2][2];   // [row-tile][k-half]
  #pragma unroll
  for (int rt = 0; rt < 2; ++rt) {
    #pragma unroll
    for (int kh = 0; kh < 2; ++kh) {
      const int i = i0 + 32 * wv + 16 * rt + cc;
      const int d0 = 32 * kh + 8 * g;
      const float* qp = qkv + (long)(i * BB + b) * E3 + hoff + d0;
      const float* rw = rwb + hoff + d0;
      const float* rr = rrb + hoff + d0;
      #pragma unroll
      for (int j = 0; j < 8; ++j) {
        float qv = qp[j];
        qw[rt][kh][j] = f2bf((qv + rw[j]) * 0.125f);
        qr[rt][kh][j] = f2bf((qv + rr[j]) * 0.125f);
      }
    }
  }

  f32x4 O[2][4];
  #pragma unroll
  for (int rt = 0; rt < 2; ++rt)
    #pragma unroll
    for (int dt = 0; dt < 4; ++dt) O[rt][dt] = (f32x4){0.f, 0.f, 0.f, 0.f};

  float mrun[2][4], lrun[2][4];
  #pragma unroll
  for (int rt = 0; rt < 2; ++rt)
    #pragma unroll
    for (int r = 0; r < 4; ++r) { mrun[rt][r] = -1e30f; lrun[rt][r] = 0.f; }

  #pragma unroll 1
  for (int it = 0; it < TT / KB; ++it) {
    const int j0 = it * KB;
    __syncthreads();

    // ---- stage K tile [32][64] bf16, 16B chunks, chunk ^= row&7 ----
    #pragma unroll
    for (int s = 0; s < 2; ++s) {
      int ch = tid + 128 * s;
      int row = ch >> 3, c8 = ch & 7;
      const float* src = qkv + (long)((j0 + row) * BB + b) * E3 + EE + hoff + c8 * 8;
      s16x8 v;
      #pragma unroll
      for (int m = 0; m < 8; ++m) v[m] = f2bf(src[m]);
      *(s16x8*)&sK[row * 64 + ((c8 ^ (row & 7)) * 8)] = v;
    }
    // ---- stage V tile [32][65] ----
    {
      int j = tid >> 2, dc = tid & 3;
      const float* src = qkv + (long)((j0 + j) * BB + b) * E3 + 2 * EE + hoff + dc * 16;
      #pragma unroll
      for (int m = 0; m < 16; ++m) sV[j * 65 + dc * 16 + m] = f2bf(src[m]);
    }
    // ---- stage p band [96][64], rows gmin..gmin+95 ----
    {
      const int gmin = j0 - i0 + 960;   // always >= 0; can reach 2047 (clamp)
      #pragma unroll
      for (int s = 0; s < 6; ++s) {
        int ch = tid + 128 * s;
        int row = ch >> 3, c8 = ch & 7;
        int prow = gmin + row;
        s16x8 v;
        if (prow < RR) {
          const float* src = pp + (long)prow * EE + hoff + c8 * 8;
          #pragma unroll
          for (int m = 0; m < 8; ++m) v[m] = f2bf(src[m]);
        } else {
          #pragma unroll
          for (int m = 0; m < 8; ++m) v[m] = 0;
        }
        *(s16x8*)&sPB[row * 64 + ((c8 ^ (row & 7)) * 8)] = v;
      }
    }
    __syncthreads();

    // ---- AC: S = qw . K^T ----
    f32x4 S[2][2];
    #pragma unroll
    for (int rt = 0; rt < 2; ++rt)
      #pragma unroll
      for (int ct = 0; ct < 2; ++ct) S[rt][ct] = (f32x4){0.f, 0.f, 0.f, 0.f};

    #pragma unroll
    for (int ct = 0; ct < 2; ++ct) {
      int krow = 16 * ct + cc;
      #pragma unroll
      for (int kh = 0; kh < 2; ++kh) {
        s16x8 kf = *(const s16x8*)&sK[krow * 64 + (((g + 4 * kh) ^ (krow & 7)) * 8)];
        #pragma unroll
        for (int rt = 0; rt < 2; ++rt)
          S[rt][ct] = __builtin_amdgcn_mfma_f32_16x16x32_bf16(qw[rt][kh], kf, S[rt][ct], 0, 0, 0);
      }
    }

    // ---- BD: Btilde = qr . pband^T, gather ul = jj + 31 - ii ----
    #pragma unroll
    for (int rt = 0; rt < 2; ++rt) {
      f32x4 bt[4];
      #pragma unroll
      for (int ut = 0; ut < 4; ++ut) bt[ut] = (f32x4){0.f, 0.f, 0.f, 0.f};
      #pragma unroll
      for (int ut = 0; ut < 4; ++ut) {
        int prl = base_w + 16 * ut + cc;
        #pragma unroll
        for (int kh = 0; kh < 2; ++kh) {
          s16x8 pf = *(const s16x8*)&sPB[prl * 64 + (((g + 4 * kh) ^ (prl & 7)) * 8)];
          bt[ut] = __builtin_amdgcn_mfma_f32_16x16x32_bf16(qr[rt][kh], pf, bt[ut], 0, 0, 0);
        }
      }
      #pragma unroll
      for (int ut = 0; ut < 4; ++ut)
        #pragma unroll
        for (int r = 0; r < 4; ++r)
          sBt[wv][(4 * g + r) * 68 + 16 * ut + cc] = bt[ut][r];
      // wave-internal LDS RAW: compiler inserts lgkmcnt
      #pragma unroll
      for (int ct = 0; ct < 2; ++ct)
        #pragma unroll
        for (int r = 0; r < 4; ++r) {
          int ii_l = 4 * g + r;
          int ul = 16 * ct + cc + 31 - 16 * rt - ii_l;   // in [0,63]
          S[rt][ct][r] += sBt[wv][ii_l * 68 + ul];
        }
    }

    // ---- online softmax per row-tile ----
    #pragma unroll
    for (int rt = 0; rt < 2; ++rt) {
      float mx[4];
      #pragma unroll
      for (int r = 0; r < 4; ++r) mx[r] = fmaxf(S[rt][0][r], S[rt][1][r]);
      #pragma unroll
      for (int msk = 1; msk < 16; msk <<= 1)
        #pragma unroll
        for (int r = 0; r < 4; ++r) mx[r] = fmaxf(mx[r], __shfl_xor(mx[r], msk, 64));
      float f[4];
      #pragma unroll
      for (int r = 0; r < 4; ++r) {
        float mn = fmaxf(mrun[rt][r], mx[r]);
        f[r] = __expf(mrun[rt][r] - mn);
        mrun[rt][r] = mn;
      }
      float sm[4];
      #pragma unroll
      for (int r = 0; r < 4; ++r) {
        S[rt][0][r] = __expf(S[rt][0][r] - mrun[rt][r]);
        S[rt][1][r] = __expf(S[rt][1][r] - mrun[rt][r]);
        sm[r] = S[rt][0][r] + S[rt][1][r];
      }
      #pragma unroll
      for (int msk = 1; msk < 16; msk <<= 1)
        #pragma unroll
        for (int r = 0; r < 4; ++r) sm[r] += __shfl_xor(sm[r], msk, 64);
      #pragma unroll
      for (int r = 0; r < 4; ++r) lrun[rt][r] = lrun[rt][r] * f[r] + sm[r];
      #pragma unroll
      for (int dt = 0; dt < 4; ++dt)
        #pragma unroll
        for (int r = 0; r < 4; ++r) O[rt][dt][r] *= f[r];
      #pragma unroll
      for (int ct = 0; ct < 2; ++ct)
        #pragma unroll
        for (int r = 0; r < 4; ++r)
          sPm[wv][(16 * rt + 4 * g + r) * 40 + 16 * ct + cc] = f2bf(S[rt][ct][r]);
    }

    // ---- V^T fragments (scalar transpose reads) ----
    s16x8 vf[4];
    #pragma unroll
    for (int dt = 0; dt < 4; ++dt)
      #pragma unroll
      for (int jj = 0; jj < 8; ++jj)
        vf[dt][jj] = sV[(8 * g + jj) * 65 + 16 * dt + cc];

    // ---- PV ----
    #pragma unroll
    for (int rt = 0; rt < 2; ++rt) {
      s16x8 pfr = *(const s16x8*)&sPm[wv][(16 * rt + cc) * 40 + 8 * g];
      #pragma unroll
      for (int dt = 0; dt < 4; ++dt)
        O[rt][dt] = __builtin_amdgcn_mfma_f32_16x16x32_bf16(pfr, vf[dt], O[rt][dt], 0, 0, 0);
    }
  }

  // ---- epilogue: ctx = O / l ----
  #pragma unroll
  for (int rt = 0; rt < 2; ++rt) {
    float rinv[4];
    #pragma unroll
    for (int r = 0; r < 4; ++r) rinv[r] = 1.0f / lrun[rt][r];
    #pragma unroll
    for (int dt = 0; dt < 4; ++dt)
      #pragma unroll
      for (int r = 0; r < 4; ++r) {
        int i = i0 + 32 * wv + 16 * rt + 4 * g + r;
        ctx[(long)(i * BB + b) * EE + hoff + 16 * dt + cc] = O[rt][dt][r] * rinv[r];
      }
  }
}

// ---------------------------------------------------------------------------
extern "C" void kernel_launch(void* const* d_in, const int* in_sizes, int n_in,
                              void* d_out, int out_size, void* d_ws, size_t ws_size,
                              hipStream_t stream) {
  const float* x      = (const float*)d_in[0];
  const float* pos    = (const float*)d_in[1];
  const float* in_w   = (const float*)d_in[2];
  const float* in_b   = (const float*)d_in[3];
  const float* pos_w  = (const float*)d_in[4];
  const float* pos_b  = (const float*)d_in[5];
  const float* out_w  = (const float*)d_in[6];
  const float* out_b  = (const float*)d_in[7];
  const float* r_w    = (const float*)d_in[8];
  const float* r_r    = (const float*)d_in[9];
  float* out = (float*)d_out;

  float* qkv = (float*)d_ws;                    // TB * 3E
  float* pp  = qkv + (long)TB * E3;             // R * E
  float* ctx = pp + (long)RR * EE;              // TB * E

  dim3 blk(256);

  gemm_bias_kernel<<<dim3(E3 / BN, TB / BM), blk, 0, stream>>>(
      x, in_w, in_b, qkv, TB, E3, EE);

  gemm_bias_kernel<<<dim3(EE / BN, (RR + BM - 1) / BM), blk, 0, stream>>>(
      pos, pos_w, pos_b, pp, RR, EE, EE);

  rel_attn_mfma<<<dim3(TT / 64, BB * HH), dim3(128), 0, stream>>>(
      qkv, pp, r_w, r_r, ctx);

  gemm_bias_kernel<<<dim3(EE / BN, TB / BM), blk, 0, stream>>>(
      ctx, out_w, out_b, out, TB, EE, EE);
}

// Round 3
// 209.258 us; speedup vs baseline: 12.7928x; 3.4672x over previous
//
#include <hip/hip_runtime.h>
#include <hip/hip_bf16.h>

// Problem constants: T=1024, B=2, E=1024, H=16, D=64, R=2*T-1
#define TT 1024
#define BB 2
#define EE 1024
#define HH 16
#define DD 64
#define RR 2047
#define TB (TT * BB)   // 2048
#define E3 (3 * EE)    // 3072

typedef __attribute__((ext_vector_type(4))) float f32x4;
typedef __attribute__((ext_vector_type(8))) short s16x8;
typedef __attribute__((ext_vector_type(4))) short s16x4;

static __device__ __forceinline__ short f2bf(float x) {
  unsigned u = __builtin_bit_cast(unsigned, x);
  unsigned r = (u + 0x7FFFu + ((u >> 16) & 1u)) >> 16;
  return (short)r;
}
static __device__ __forceinline__ float bf2f(short x) {
  unsigned u = ((unsigned)(unsigned short)x) << 16;
  return __builtin_bit_cast(float, u);
}

// ---------------------------------------------------------------------------
// fp32 -> bf16 convert, 8 elems/thread; zero-pads [nsrc, n)
// ---------------------------------------------------------------------------
__global__ __launch_bounds__(256) void cvt_f32_bf16(
    const float* __restrict__ src, short* __restrict__ dst, int n, int nsrc) {
  int i = (blockIdx.x * 256 + threadIdx.x) * 8;
  if (i >= n) return;
  s16x8 o;
  if (i + 8 <= nsrc) {
    f32x4 a = *(const f32x4*)&src[i];
    f32x4 c = *(const f32x4*)&src[i + 4];
    #pragma unroll
    for (int j = 0; j < 4; ++j) { o[j] = f2bf(a[j]); o[4 + j] = f2bf(c[j]); }
  } else {
    #pragma unroll
    for (int j = 0; j < 8; ++j) o[j] = 0;
  }
  *(s16x8*)&dst[i] = o;
}

// ---------------------------------------------------------------------------
// bf16 MFMA GEMM (m97 structure): C[M,N] = A[M,K] @ W[N,K]^T + bias[N]
//   128x128 tile, BK=32, 256 thr (4 waves, 2x2 quadrants of 64x64)
//   double-buffered LDS, global_load_lds width=16, chunk-XOR swizzle
//   (swizzle applied on BOTH sides: pre-swizzled global source for the
//    linear global_load_lds dest + swizzled ds_read — rule #21)
// M, N must be multiples of 128; K multiple of 32.
// ---------------------------------------------------------------------------
#define GBM 128
#define GBN 128
#define GBK 32

template <int OUT_BF16>
__global__ __launch_bounds__(256) void gemm_bf16_mfma(
    const short* __restrict__ A, const short* __restrict__ W,
    const float* __restrict__ bias, void* __restrict__ Cout,
    int M, int N, int K) {
  __shared__ __align__(16) short lA[2][GBM * GBK];
  __shared__ __align__(16) short lB[2][GBN * GBK];

  const int tid = threadIdx.x;
  const int lane = tid & 63;
  const int wv = tid >> 6;
  const int g = lane >> 4, cc = lane & 15;
  const int wr = wv >> 1, wc = wv & 1;
  const int m0 = blockIdx.y * GBM, n0 = blockIdx.x * GBN;

  f32x4 acc[4][4];
  #pragma unroll
  for (int i = 0; i < 4; ++i)
    #pragma unroll
    for (int j = 0; j < 4; ++j) acc[i][j] = (f32x4){0.f, 0.f, 0.f, 0.f};

#define STAGE_TILE(kk_, buf_)                                                  \
  {                                                                            \
    _Pragma("unroll")                                                          \
    for (int s = 0; s < 2; ++s) {                                              \
      int c = s * 256 + tid;                                                   \
      int row = c >> 2, slot = c & 3;                                          \
      int k8 = slot ^ (row & 3);                                               \
      __builtin_amdgcn_global_load_lds(                                        \
          (const __attribute__((address_space(1))) void*)(A + (size_t)(m0 + row) * K + (kk_) + k8 * 8), \
          (__attribute__((address_space(3))) void*)&lA[buf_][c * 8], 16, 0, 0);\
      __builtin_amdgcn_global_load_lds(                                        \
          (const __attribute__((address_space(1))) void*)(W + (size_t)(n0 + row) * K + (kk_) + k8 * 8), \
          (__attribute__((address_space(3))) void*)&lB[buf_][c * 8], 16, 0, 0);\
    }                                                                          \
  }

  int cur = 0;
  const int nt = K / GBK;
  STAGE_TILE(0, 0);

  #pragma unroll 1
  for (int t = 0; t < nt; ++t) {
    __syncthreads();   // vmcnt(0)+lgkmcnt(0)+barrier: buf[cur] ready, buf[cur^1] free
    if (t + 1 < nt) STAGE_TILE((t + 1) * GBK, cur ^ 1);

    s16x8 af[4], bf[4];
    #pragma unroll
    for (int mt = 0; mt < 4; ++mt) {
      int row = 64 * wr + 16 * mt + cc;
      af[mt] = *(const s16x8*)&lA[cur][row * GBK + ((g ^ (row & 3)) * 8)];
    }
    #pragma unroll
    for (int ntc = 0; ntc < 4; ++ntc) {
      int col = 64 * wc + 16 * ntc + cc;
      bf[ntc] = *(const s16x8*)&lB[cur][col * GBK + ((g ^ (col & 3)) * 8)];
    }
    #pragma unroll
    for (int mt = 0; mt < 4; ++mt)
      #pragma unroll
      for (int ntc = 0; ntc < 4; ++ntc)
        acc[mt][ntc] = __builtin_amdgcn_mfma_f32_16x16x32_bf16(
            af[mt], bf[ntc], acc[mt][ntc], 0, 0, 0);
    cur ^= 1;
  }
#undef STAGE_TILE

  // epilogue: C/D layout col=lane&15, row=(lane>>4)*4+reg
  #pragma unroll
  for (int ntc = 0; ntc < 4; ++ntc) {
    int col = n0 + 64 * wc + 16 * ntc + cc;
    float bv = bias[col];
    #pragma unroll
    for (int mt = 0; mt < 4; ++mt)
      #pragma unroll
      for (int r = 0; r < 4; ++r) {
        int rowg = m0 + 64 * wr + 16 * mt + 4 * g + r;
        float val = acc[mt][ntc][r] + bv;
        if (OUT_BF16)
          ((short*)Cout)[(size_t)rowg * N + col] = f2bf(val);
        else
          ((float*)Cout)[(size_t)rowg * N + col] = val;
      }
  }
}

// ---------------------------------------------------------------------------
// MFMA flash attention with folded relative shift (bf16 in, bf16 out).
//   score[i,j] = qw_i.k_j + qr_i.p[j-i+1023]   (1/8 scale folded into qw,qr)
// ---------------------------------------------------------------------------
#define KB 32
#define AW 2

__global__ __launch_bounds__(128) void rel_attn_mfma(
    const short* __restrict__ qkvb,  // [TB][3E] bf16
    const short* __restrict__ pb,    // [2048][E] bf16 (row 2047 unused)
    const float* __restrict__ rwb,   // [H*D]
    const float* __restrict__ rrb,   // [H*D]
    short* __restrict__ ctxb) {      // [TB][E] bf16
  __shared__ __align__(16) short sK[KB * 64];        // chunk-swizzled
  __shared__ __align__(16) short sPB[96 * 64];       // chunk-swizzled
  __shared__ __align__(16) short sV[KB * 68];        // stride 68 (bank spread)
  __shared__ __align__(16) float sBt[AW][16 * 68];   // Btilde scratch
  __shared__ __align__(16) short sPm[AW][32 * 40];   // P round-trip

  const int tid = threadIdx.x;
  const int wv = tid >> 6;
  const int lane = tid & 63;
  const int g = lane >> 4;
  const int cc = lane & 15;
  const int i0 = blockIdx.x * 64;
  const int bh = blockIdx.y;
  const int b = bh >> 4, h = bh & 15;
  const int hoff = h * DD;
  const int base_w = 32 * (1 - wv);

  // ---- Q fragments (scale folded) ----
  s16x8 qw[2][2], qr[2][2];
  #pragma unroll
  for (int rt = 0; rt < 2; ++rt) {
    #pragma unroll
    for (int kh = 0; kh < 2; ++kh) {
      const int i = i0 + 32 * wv + 16 * rt + cc;
      const int d0 = 32 * kh + 8 * g;
      const short* qp = qkvb + (size_t)(i * BB + b) * E3 + hoff + d0;
      const float* rw = rwb + hoff + d0;
      const float* rr = rrb + hoff + d0;
      s16x8 qv = *(const s16x8*)qp;
      #pragma unroll
      for (int j = 0; j < 8; ++j) {
        float q = bf2f(qv[j]);
        qw[rt][kh][j] = f2bf((q + rw[j]) * 0.125f);
        qr[rt][kh][j] = f2bf((q + rr[j]) * 0.125f);
      }
    }
  }

  f32x4 O[2][4];
  #pragma unroll
  for (int rt = 0; rt < 2; ++rt)
    #pragma unroll
    for (int dt = 0; dt < 4; ++dt) O[rt][dt] = (f32x4){0.f, 0.f, 0.f, 0.f};

  float mrun[2][4], lrun[2][4];
  #pragma unroll
  for (int rt = 0; rt < 2; ++rt)
    #pragma unroll
    for (int r = 0; r < 4; ++r) { mrun[rt][r] = -1e30f; lrun[rt][r] = 0.f; }

  #pragma unroll 1
  for (int it = 0; it < TT / KB; ++it) {
    const int j0 = it * KB;
    __syncthreads();

    // ---- stage K tile [32][64], 16B chunks, chunk ^= row&7 ----
    #pragma unroll
    for (int s = 0; s < 2; ++s) {
      int ch = tid + 128 * s;
      int row = ch >> 3, c8 = ch & 7;
      const short* src = qkvb + (size_t)((j0 + row) * BB + b) * E3 + EE + hoff + c8 * 8;
      *(s16x8*)&sK[row * 64 + ((c8 ^ (row & 7)) * 8)] = *(const s16x8*)src;
    }
    // ---- stage V tile [32][68] ----
    {
      int j = tid >> 2, dc = tid & 3;
      const short* src = qkvb + (size_t)((j0 + j) * BB + b) * E3 + 2 * EE + hoff + dc * 16;
      s16x8 v0 = *(const s16x8*)src;
      s16x8 v1 = *(const s16x8*)(src + 8);
      short* dst = &sV[j * 68 + dc * 16];
      *(s16x4*)(dst + 0)  = __builtin_shufflevector(v0, v0, 0, 1, 2, 3);
      *(s16x4*)(dst + 4)  = __builtin_shufflevector(v0, v0, 4, 5, 6, 7);
      *(s16x4*)(dst + 8)  = __builtin_shufflevector(v1, v1, 0, 1, 2, 3);
      *(s16x4*)(dst + 12) = __builtin_shufflevector(v1, v1, 4, 5, 6, 7);
    }
    // ---- stage p band [96][64], rows gmin..gmin+95 ----
    {
      const int gmin = j0 - i0 + 960;
      #pragma unroll
      for (int s = 0; s < 6; ++s) {
        int ch = tid + 128 * s;
        int row = ch >> 3, c8 = ch & 7;
        int prow = gmin + row;
        s16x8 v;
        if (prow < RR) {
          v = *(const s16x8*)(pb + (size_t)prow * EE + hoff + c8 * 8);
        } else {
          #pragma unroll
          for (int m = 0; m < 8; ++m) v[m] = 0;
        }
        *(s16x8*)&sPB[row * 64 + ((c8 ^ (row & 7)) * 8)] = v;
      }
    }
    __syncthreads();

    // ---- AC: S = qw . K^T ----
    f32x4 S[2][2];
    #pragma unroll
    for (int rt = 0; rt < 2; ++rt)
      #pragma unroll
      for (int ct = 0; ct < 2; ++ct) S[rt][ct] = (f32x4){0.f, 0.f, 0.f, 0.f};

    #pragma unroll
    for (int ct = 0; ct < 2; ++ct) {
      int krow = 16 * ct + cc;
      #pragma unroll
      for (int kh = 0; kh < 2; ++kh) {
        s16x8 kf = *(const s16x8*)&sK[krow * 64 + (((g + 4 * kh) ^ (krow & 7)) * 8)];
        #pragma unroll
        for (int rt = 0; rt < 2; ++rt)
          S[rt][ct] = __builtin_amdgcn_mfma_f32_16x16x32_bf16(qw[rt][kh], kf, S[rt][ct], 0, 0, 0);
      }
    }

    // ---- BD: Btilde = qr . pband^T, gather ul = jj + 31 - ii ----
    #pragma unroll
    for (int rt = 0; rt < 2; ++rt) {
      f32x4 bt[4];
      #pragma unroll
      for (int ut = 0; ut < 4; ++ut) bt[ut] = (f32x4){0.f, 0.f, 0.f, 0.f};
      #pragma unroll
      for (int ut = 0; ut < 4; ++ut) {
        int prl = base_w + 16 * ut + cc;
        #pragma unroll
        for (int kh = 0; kh < 2; ++kh) {
          s16x8 pf = *(const s16x8*)&sPB[prl * 64 + (((g + 4 * kh) ^ (prl & 7)) * 8)];
          bt[ut] = __builtin_amdgcn_mfma_f32_16x16x32_bf16(qr[rt][kh], pf, bt[ut], 0, 0, 0);
        }
      }
      #pragma unroll
      for (int ut = 0; ut < 4; ++ut)
        #pragma unroll
        for (int r = 0; r < 4; ++r)
          sBt[wv][(4 * g + r) * 68 + 16 * ut + cc] = bt[ut][r];
      #pragma unroll
      for (int ct = 0; ct < 2; ++ct)
        #pragma unroll
        for (int r = 0; r < 4; ++r) {
          int ii_l = 4 * g + r;
          int ul = 16 * ct + cc + 31 - 16 * rt - ii_l;   // in [0,63]
          S[rt][ct][r] += sBt[wv][ii_l * 68 + ul];
        }
    }

    // ---- online softmax per row-tile ----
    #pragma unroll
    for (int rt = 0; rt < 2; ++rt) {
      float mx[4];
      #pragma unroll
      for (int r = 0; r < 4; ++r) mx[r] = fmaxf(S[rt][0][r], S[rt][1][r]);
      #pragma unroll
      for (int msk = 1; msk < 16; msk <<= 1)
        #pragma unroll
        for (int r = 0; r < 4; ++r) mx[r] = fmaxf(mx[r], __shfl_xor(mx[r], msk, 64));
      float f[4];
      #pragma unroll
      for (int r = 0; r < 4; ++r) {
        float mn = fmaxf(mrun[rt][r], mx[r]);
        f[r] = __expf(mrun[rt][r] - mn);
        mrun[rt][r] = mn;
      }
      float sm[4];
      #pragma unroll
      for (int r = 0; r < 4; ++r) {
        S[rt][0][r] = __expf(S[rt][0][r] - mrun[rt][r]);
        S[rt][1][r] = __expf(S[rt][1][r] - mrun[rt][r]);
        sm[r] = S[rt][0][r] + S[rt][1][r];
      }
      #pragma unroll
      for (int msk = 1; msk < 16; msk <<= 1)
        #pragma unroll
        for (int r = 0; r < 4; ++r) sm[r] += __shfl_xor(sm[r], msk, 64);
      #pragma unroll
      for (int r = 0; r < 4; ++r) lrun[rt][r] = lrun[rt][r] * f[r] + sm[r];
      #pragma unroll
      for (int dt = 0; dt < 4; ++dt)
        #pragma unroll
        for (int r = 0; r < 4; ++r) O[rt][dt][r] *= f[r];
      #pragma unroll
      for (int ct = 0; ct < 2; ++ct)
        #pragma unroll
        for (int r = 0; r < 4; ++r)
          sPm[wv][(16 * rt + 4 * g + r) * 40 + 16 * ct + cc] = f2bf(S[rt][ct][r]);
    }

    // ---- V^T fragments (scalar transpose reads) ----
    s16x8 vf[4];
    #pragma unroll
    for (int dt = 0; dt < 4; ++dt)
      #pragma unroll
      for (int jj = 0; jj < 8; ++jj)
        vf[dt][jj] = sV[(8 * g + jj) * 68 + 16 * dt + cc];

    // ---- PV ----
    #pragma unroll
    for (int rt = 0; rt < 2; ++rt) {
      s16x8 pfr = *(const s16x8*)&sPm[wv][(16 * rt + cc) * 40 + 8 * g];
      #pragma unroll
      for (int dt = 0; dt < 4; ++dt)
        O[rt][dt] = __builtin_amdgcn_mfma_f32_16x16x32_bf16(pfr, vf[dt], O[rt][dt], 0, 0, 0);
    }
  }

  // ---- epilogue: ctx = O / l  (bf16) ----
  #pragma unroll
  for (int rt = 0; rt < 2; ++rt) {
    float rinv[4];
    #pragma unroll
    for (int r = 0; r < 4; ++r) rinv[r] = 1.0f / lrun[rt][r];
    #pragma unroll
    for (int dt = 0; dt < 4; ++dt)
      #pragma unroll
      for (int r = 0; r < 4; ++r) {
        int i = i0 + 32 * wv + 16 * rt + 4 * g + r;
        ctxb[(size_t)(i * BB + b) * EE + hoff + 16 * dt + cc] = f2bf(O[rt][dt][r] * rinv[r]);
      }
  }
}

// ---------------------------------------------------------------------------
extern "C" void kernel_launch(void* const* d_in, const int* in_sizes, int n_in,
                              void* d_out, int out_size, void* d_ws, size_t ws_size,
                              hipStream_t stream) {
  const float* x      = (const float*)d_in[0];
  const float* pos    = (const float*)d_in[1];
  const float* in_w   = (const float*)d_in[2];
  const float* in_b   = (const float*)d_in[3];
  const float* pos_w  = (const float*)d_in[4];
  const float* pos_b  = (const float*)d_in[5];
  const float* out_w  = (const float*)d_in[6];
  const float* out_b  = (const float*)d_in[7];
  const float* r_w    = (const float*)d_in[8];
  const float* r_r    = (const float*)d_in[9];
  float* out = (float*)d_out;

  const size_t M1 = 1024 * 1024;
  short* xb    = (short*)d_ws;        // 2M
  short* inwb  = xb    + 2 * M1;      // 3M
  short* posb  = inwb  + 3 * M1;      // 2M (2048 rows, row 2047 zeroed)
  short* poswb = posb  + 2 * M1;      // 1M
  short* outwb = poswb + 1 * M1;      // 1M
  short* qkvb  = outwb + 1 * M1;      // 6M
  short* pb    = qkvb  + 6 * M1;      // 2M
  short* ctxb  = pb    + 2 * M1;      // 2M

  // ---- converts ----
  cvt_f32_bf16<<<dim3(2 * M1 / 8 / 256), dim3(256), 0, stream>>>(x, xb, 2 * M1, 2 * M1);
  cvt_f32_bf16<<<dim3(3 * M1 / 8 / 256), dim3(256), 0, stream>>>(in_w, inwb, 3 * M1, 3 * M1);
  cvt_f32_bf16<<<dim3(2 * M1 / 8 / 256), dim3(256), 0, stream>>>(pos, posb, 2 * M1, RR * EE);
  cvt_f32_bf16<<<dim3(M1 / 8 / 256), dim3(256), 0, stream>>>(pos_w, poswb, M1, M1);
  cvt_f32_bf16<<<dim3(M1 / 8 / 256), dim3(256), 0, stream>>>(out_w, outwb, M1, M1);

  // ---- qkv = x @ in_w^T + in_b   [2048 x 3072], bf16 out ----
  gemm_bf16_mfma<1><<<dim3(E3 / GBN, TB / GBM), dim3(256), 0, stream>>>(
      xb, inwb, in_b, qkvb, TB, E3, EE);

  // ---- p = pos @ pos_w^T + pos_b  [2048 x 1024], bf16 out ----
  gemm_bf16_mfma<1><<<dim3(EE / GBN, 2048 / GBM), dim3(256), 0, stream>>>(
      posb, poswb, pos_b, pb, 2048, EE, EE);

  // ---- attention -> ctx (bf16) ----
  rel_attn_mfma<<<dim3(TT / 64, BB * HH), dim3(128), 0, stream>>>(
      qkvb, pb, r_w, r_r, ctxb);

  // ---- out = ctx @ out_w^T + out_b  [2048 x 1024], fp32 out ----
  gemm_bf16_mfma<0><<<dim3(EE / GBN, TB / GBM), dim3(256), 0, stream>>>(
      ctxb, outwb, out_b, out, TB, EE, EE);
}

// Round 4
// 182.137 us; speedup vs baseline: 14.6977x; 1.1489x over previous
//
#include <hip/hip_runtime.h>
#include <hip/hip_bf16.h>

// Problem constants: T=1024, B=2, E=1024, H=16, D=64, R=2*T-1
#define TT 1024
#define BB 2
#define EE 1024
#define HH 16
#define DD 64
#define RR 2047
#define TB (TT * BB)   // 2048
#define E3 (3 * EE)    // 3072

typedef __attribute__((ext_vector_type(4))) float f32x4;
typedef __attribute__((ext_vector_type(8))) short s16x8;

static __device__ __forceinline__ short f2bf(float x) {
  unsigned u = __builtin_bit_cast(unsigned, x);
  unsigned r = (u + 0x7FFFu + ((u >> 16) & 1u)) >> 16;
  return (short)r;
}
static __device__ __forceinline__ float bf2f(short x) {
  unsigned u = ((unsigned)(unsigned short)x) << 16;
  return __builtin_bit_cast(float, u);
}

// ---------------------------------------------------------------------------
// fp32 -> bf16 convert, 8 elems/thread; zero-pads [nsrc, n)
// ---------------------------------------------------------------------------
__global__ __launch_bounds__(256) void cvt_f32_bf16(
    const float* __restrict__ src, short* __restrict__ dst, int n, int nsrc) {
  int i = (blockIdx.x * 256 + threadIdx.x) * 8;
  if (i >= n) return;
  s16x8 o;
  if (i + 8 <= nsrc) {
    f32x4 a = *(const f32x4*)&src[i];
    f32x4 c = *(const f32x4*)&src[i + 4];
    #pragma unroll
    for (int j = 0; j < 4; ++j) { o[j] = f2bf(a[j]); o[4 + j] = f2bf(c[j]); }
  } else {
    #pragma unroll
    for (int j = 0; j < 8; ++j) o[j] = 0;
  }
  *(s16x8*)&dst[i] = o;
}

// ---------------------------------------------------------------------------
// bf16 MFMA GEMM (m97 structure): C[M,N] = A[M,K] @ W[N,K]^T + bias[N]
// ---------------------------------------------------------------------------
#define GBM 128
#define GBN 128
#define GBK 32

template <int OUT_BF16>
__global__ __launch_bounds__(256) void gemm_bf16_mfma(
    const short* __restrict__ A, const short* __restrict__ W,
    const float* __restrict__ bias, void* __restrict__ Cout,
    int M, int N, int K) {
  __shared__ __align__(16) short lA[2][GBM * GBK];
  __shared__ __align__(16) short lB[2][GBN * GBK];

  const int tid = threadIdx.x;
  const int lane = tid & 63;
  const int wv = tid >> 6;
  const int g = lane >> 4, cc = lane & 15;
  const int wr = wv >> 1, wc = wv & 1;
  const int m0 = blockIdx.y * GBM, n0 = blockIdx.x * GBN;

  f32x4 acc[4][4];
  #pragma unroll
  for (int i = 0; i < 4; ++i)
    #pragma unroll
    for (int j = 0; j < 4; ++j) acc[i][j] = (f32x4){0.f, 0.f, 0.f, 0.f};

#define STAGE_TILE(kk_, buf_)                                                  \
  {                                                                            \
    _Pragma("unroll")                                                          \
    for (int s = 0; s < 2; ++s) {                                              \
      int c = s * 256 + tid;                                                   \
      int row = c >> 2, slot = c & 3;                                          \
      int k8 = slot ^ (row & 3);                                               \
      __builtin_amdgcn_global_load_lds(                                        \
          (const __attribute__((address_space(1))) void*)(A + (size_t)(m0 + row) * K + (kk_) + k8 * 8), \
          (__attribute__((address_space(3))) void*)&lA[buf_][c * 8], 16, 0, 0);\
      __builtin_amdgcn_global_load_lds(                                        \
          (const __attribute__((address_space(1))) void*)(W + (size_t)(n0 + row) * K + (kk_) + k8 * 8), \
          (__attribute__((address_space(3))) void*)&lB[buf_][c * 8], 16, 0, 0);\
    }                                                                          \
  }

  int cur = 0;
  const int nt = K / GBK;
  STAGE_TILE(0, 0);

  #pragma unroll 1
  for (int t = 0; t < nt; ++t) {
    __syncthreads();
    if (t + 1 < nt) STAGE_TILE((t + 1) * GBK, cur ^ 1);

    s16x8 af[4], bf[4];
    #pragma unroll
    for (int mt = 0; mt < 4; ++mt) {
      int row = 64 * wr + 16 * mt + cc;
      af[mt] = *(const s16x8*)&lA[cur][row * GBK + ((g ^ (row & 3)) * 8)];
    }
    #pragma unroll
    for (int ntc = 0; ntc < 4; ++ntc) {
      int col = 64 * wc + 16 * ntc + cc;
      bf[ntc] = *(const s16x8*)&lB[cur][col * GBK + ((g ^ (col & 3)) * 8)];
    }
    #pragma unroll
    for (int mt = 0; mt < 4; ++mt)
      #pragma unroll
      for (int ntc = 0; ntc < 4; ++ntc)
        acc[mt][ntc] = __builtin_amdgcn_mfma_f32_16x16x32_bf16(
            af[mt], bf[ntc], acc[mt][ntc], 0, 0, 0);
    cur ^= 1;
  }
#undef STAGE_TILE

  #pragma unroll
  for (int ntc = 0; ntc < 4; ++ntc) {
    int col = n0 + 64 * wc + 16 * ntc + cc;
    float bv = bias[col];
    #pragma unroll
    for (int mt = 0; mt < 4; ++mt)
      #pragma unroll
      for (int r = 0; r < 4; ++r) {
        int rowg = m0 + 64 * wr + 16 * mt + 4 * g + r;
        float val = acc[mt][ntc][r] + bv;
        if (OUT_BF16)
          ((short*)Cout)[(size_t)rowg * N + col] = f2bf(val);
        else
          ((float*)Cout)[(size_t)rowg * N + col] = val;
      }
  }
}

// ---------------------------------------------------------------------------
// MFMA flash attention, occupancy-oriented:
//   grid (T/16=64, B*H=32); 2 waves/block; both waves own the same 16 q-rows,
//   wave w handles key tiles [16w, 16w+16) (512 keys) with private online
//   softmax; merge at the end via LDS (one barrier total).
//   K and p-band MFMA B-fragments are read DIRECTLY from global (16B/lane,
//   L2-served); only V is LDS-staged (transpose access needed).
//   score[i,j] = qw_i.k_j + qr_i.p[j-i+1023]  (1/8 scale folded into qw,qr)
//   BD: Btilde[ii][u] = qr_i . p[gmin+u], u = jj-ii+15 in [0,46], 3 ut-tiles;
//       gmin = j0-iq0+1008; max row touched = 2047 = zero-padded row of pb.
// LDS arena (17920 B), wave-private slots; loop phase has NO barriers:
//   sV[w]  = arena +     w*4352   : short[32][68]
//   sBt[w] = arena + 8704 + w*3200: float[16][50]
//   sPm[w] = arena + 15104 + w*1280: short[16][40]
//   epilogue alias: sO[w] = arena + w*4352 (float[16][68]); sML = arena+17664
// ---------------------------------------------------------------------------
#define QB 16

__global__ __launch_bounds__(128, 4) void rel_attn_mfma2(
    const short* __restrict__ qkvb,  // [TB][3E] bf16
    const short* __restrict__ pb,    // [2048][E] bf16 (row 2047 zeroed)
    const float* __restrict__ rwb,   // [H*D]
    const float* __restrict__ rrb,   // [H*D]
    short* __restrict__ ctxb) {      // [TB][E] bf16
  __shared__ __align__(16) char arena[17920];

  const int tid = threadIdx.x;
  const int wv = tid >> 6;
  const int lane = tid & 63;
  const int g = lane >> 4;      // 0..3
  const int cc = lane & 15;     // 0..15
  const int iq0 = blockIdx.x * QB;
  const int bh = blockIdx.y;
  const int b = bh >> 4, h = bh & 15;
  const int hoff = h * DD;

  short* sV  = (short*)(arena + wv * 4352);            // [32][68]
  float* sBt = (float*)(arena + 8704 + wv * 3200);     // [16][50]
  short* sPm = (short*)(arena + 15104 + wv * 1280);    // [16][40]

  // ---- Q fragments: row = cc (q row iq0+cc), k-pack d = 32*kh + 8*g ----
  s16x8 qw[2], qr[2];
  #pragma unroll
  for (int kh = 0; kh < 2; ++kh) {
    const int d0 = 32 * kh + 8 * g;
    const short* qp = qkvb + (size_t)((iq0 + cc) * BB + b) * E3 + hoff + d0;
    const float* rw = rwb + hoff + d0;
    const float* rr = rrb + hoff + d0;
    s16x8 qv = *(const s16x8*)qp;
    #pragma unroll
    for (int j = 0; j < 8; ++j) {
      float q = bf2f(qv[j]);
      qw[kh][j] = f2bf((q + rw[j]) * 0.125f);
      qr[kh][j] = f2bf((q + rr[j]) * 0.125f);
    }
  }

  f32x4 O[4];
  #pragma unroll
  for (int dt = 0; dt < 4; ++dt) O[dt] = (f32x4){0.f, 0.f, 0.f, 0.f};
  float mrun[4], lrun[4];
  #pragma unroll
  for (int r = 0; r < 4; ++r) { mrun[r] = -1e30f; lrun[r] = 0.f; }

  #pragma unroll 1
  for (int t = 0; t < 16; ++t) {
    const int j0 = (16 * wv + t) * 32;     // this wave's key tile base

    // ---- stage V tile [32][64] -> sV [32][68] (wave-private, no barrier) ----
    #pragma unroll
    for (int c = 0; c < 4; ++c) {
      int id = c * 64 + lane;
      int row = id >> 3, c8 = id & 7;
      const short* src = qkvb + (size_t)((j0 + row) * BB + b) * E3 + 2 * EE + hoff + c8 * 8;
      *(s16x8*)&sV[row * 68 + c8 * 8] = *(const s16x8*)src;
    }

    // ---- AC: S[ct] = qw . K^T, K fragments direct from global ----
    s16x8 kf[2][2];
    #pragma unroll
    for (int ct = 0; ct < 2; ++ct)
      #pragma unroll
      for (int kh = 0; kh < 2; ++kh)
        kf[ct][kh] = *(const s16x8*)(qkvb + (size_t)((j0 + 16 * ct + cc) * BB + b) * E3 + EE + hoff + 32 * kh + 8 * g);

    f32x4 S[2];
    #pragma unroll
    for (int ct = 0; ct < 2; ++ct) {
      S[ct] = (f32x4){0.f, 0.f, 0.f, 0.f};
      #pragma unroll
      for (int kh = 0; kh < 2; ++kh)
        S[ct] = __builtin_amdgcn_mfma_f32_16x16x32_bf16(qw[kh], kf[ct][kh], S[ct], 0, 0, 0);
    }

    // ---- BD: Btilde = qr . pband^T (3 ut tiles), band direct from global ----
    const int gmin = j0 - iq0 + 1008;
    f32x4 bt[3];
    #pragma unroll
    for (int ut = 0; ut < 3; ++ut) {
      const int prl = gmin + 16 * ut + cc;   // <= 2047 (row 2047 is zeros)
      bt[ut] = (f32x4){0.f, 0.f, 0.f, 0.f};
      #pragma unroll
      for (int kh = 0; kh < 2; ++kh) {
        s16x8 pf = *(const s16x8*)(pb + (size_t)prl * EE + hoff + 32 * kh + 8 * g);
        bt[ut] = __builtin_amdgcn_mfma_f32_16x16x32_bf16(qr[kh], pf, bt[ut], 0, 0, 0);
      }
    }
    #pragma unroll
    for (int ut = 0; ut < 3; ++ut)
      #pragma unroll
      for (int r = 0; r < 4; ++r)
        sBt[(4 * g + r) * 50 + 16 * ut + cc] = bt[ut][r];
    // wave-internal LDS RAW: compiler inserts lgkmcnt
    #pragma unroll
    for (int ct = 0; ct < 2; ++ct)
      #pragma unroll
      for (int r = 0; r < 4; ++r) {
        int ii = 4 * g + r;
        S[ct][r] += sBt[ii * 50 + (16 * ct + cc + 15 - ii)];   // col in [0,46]
      }

    // ---- online softmax (rows = 4g+r, cols spread over cc and ct) ----
    float mx[4];
    #pragma unroll
    for (int r = 0; r < 4; ++r) mx[r] = fmaxf(S[0][r], S[1][r]);
    #pragma unroll
    for (int msk = 1; msk < 16; msk <<= 1)
      #pragma unroll
      for (int r = 0; r < 4; ++r) mx[r] = fmaxf(mx[r], __shfl_xor(mx[r], msk, 64));
    float f[4], sm[4];
    #pragma unroll
    for (int r = 0; r < 4; ++r) {
      float mn = fmaxf(mrun[r], mx[r]);
      f[r] = __expf(mrun[r] - mn);
      mrun[r] = mn;
      S[0][r] = __expf(S[0][r] - mn);
      S[1][r] = __expf(S[1][r] - mn);
      sm[r] = S[0][r] + S[1][r];
    }
    #pragma unroll
    for (int msk = 1; msk < 16; msk <<= 1)
      #pragma unroll
      for (int r = 0; r < 4; ++r) sm[r] += __shfl_xor(sm[r], msk, 64);
    #pragma unroll
    for (int r = 0; r < 4; ++r) lrun[r] = lrun[r] * f[r] + sm[r];
    #pragma unroll
    for (int dt = 0; dt < 4; ++dt)
      #pragma unroll
      for (int r = 0; r < 4; ++r) O[dt][r] *= f[r];

    // ---- P to A-fragment layout via wave-private LDS ----
    #pragma unroll
    for (int ct = 0; ct < 2; ++ct)
      #pragma unroll
      for (int r = 0; r < 4; ++r)
        sPm[(4 * g + r) * 40 + 16 * ct + cc] = f2bf(S[ct][r]);

    s16x8 pa = *(const s16x8*)&sPm[cc * 40 + 8 * g];

    // ---- V^T fragments (scalar transpose reads) + PV ----
    s16x8 vf[4];
    #pragma unroll
    for (int dt = 0; dt < 4; ++dt)
      #pragma unroll
      for (int jj = 0; jj < 8; ++jj)
        vf[dt][jj] = sV[(8 * g + jj) * 68 + 16 * dt + cc];
    #pragma unroll
    for (int dt = 0; dt < 4; ++dt)
      O[dt] = __builtin_amdgcn_mfma_f32_16x16x32_bf16(pa, vf[dt], O[dt], 0, 0, 0);
  }

  // ---- merge the two waves' partial (O, m, l) ----
  float* sO0 = (float*)(arena);                 // wave0 O  [16][68]
  float* sO1 = (float*)(arena + 4352);          // wave1 O  [16][68]
  float* sML = (float*)(arena + 17664);         // [w][2][16]
  float* sOw = wv ? sO1 : sO0;
  #pragma unroll
  for (int dt = 0; dt < 4; ++dt)
    #pragma unroll
    for (int r = 0; r < 4; ++r)
      sOw[(4 * g + r) * 68 + 16 * dt + cc] = O[dt][r];
  if (cc == 0) {
    #pragma unroll
    for (int r = 0; r < 4; ++r) {
      sML[wv * 32 + (4 * g + r)] = mrun[r];
      sML[wv * 32 + 16 + (4 * g + r)] = lrun[r];
    }
  }
  __syncthreads();

  #pragma unroll
  for (int r = 0; r < 4; ++r) {
    const int ii = 4 * g + r;
    const float m0 = sML[ii], l0 = sML[16 + ii];
    const float m1 = sML[32 + ii], l1 = sML[48 + ii];
    const float M = fmaxf(m0, m1);
    const float f0 = __expf(m0 - M), f1 = __expf(m1 - M);
    const float rinv = 1.0f / (f0 * l0 + f1 * l1);
    #pragma unroll
    for (int dt2 = 0; dt2 < 2; ++dt2) {
      const int dt = 2 * wv + dt2;
      const int col = 16 * dt + cc;
      const float val = (f0 * sO0[ii * 68 + col] + f1 * sO1[ii * 68 + col]) * rinv;
      ctxb[(size_t)((iq0 + ii) * BB + b) * EE + hoff + col] = f2bf(val);
    }
  }
}

// ---------------------------------------------------------------------------
extern "C" void kernel_launch(void* const* d_in, const int* in_sizes, int n_in,
                              void* d_out, int out_size, void* d_ws, size_t ws_size,
                              hipStream_t stream) {
  const float* x      = (const float*)d_in[0];
  const float* pos    = (const float*)d_in[1];
  const float* in_w   = (const float*)d_in[2];
  const float* in_b   = (const float*)d_in[3];
  const float* pos_w  = (const float*)d_in[4];
  const float* pos_b  = (const float*)d_in[5];
  const float* out_w  = (const float*)d_in[6];
  const float* out_b  = (const float*)d_in[7];
  const float* r_w    = (const float*)d_in[8];
  const float* r_r    = (const float*)d_in[9];
  float* out = (float*)d_out;

  const size_t M1 = 1024 * 1024;
  short* xb    = (short*)d_ws;        // 2M
  short* inwb  = xb    + 2 * M1;      // 3M
  short* posb  = inwb  + 3 * M1;      // 2M (2048 rows, row 2047 zeroed)
  short* poswb = posb  + 2 * M1;      // 1M
  short* outwb = poswb + 1 * M1;      // 1M
  short* qkvb  = outwb + 1 * M1;      // 6M
  short* pb    = qkvb  + 6 * M1;      // 2M
  short* ctxb  = pb    + 2 * M1;      // 2M

  cvt_f32_bf16<<<dim3(2 * M1 / 8 / 256), dim3(256), 0, stream>>>(x, xb, 2 * M1, 2 * M1);
  cvt_f32_bf16<<<dim3(3 * M1 / 8 / 256), dim3(256), 0, stream>>>(in_w, inwb, 3 * M1, 3 * M1);
  cvt_f32_bf16<<<dim3(2 * M1 / 8 / 256), dim3(256), 0, stream>>>(pos, posb, 2 * M1, RR * EE);
  cvt_f32_bf16<<<dim3(M1 / 8 / 256), dim3(256), 0, stream>>>(pos_w, poswb, M1, M1);
  cvt_f32_bf16<<<dim3(M1 / 8 / 256), dim3(256), 0, stream>>>(out_w, outwb, M1, M1);

  gemm_bf16_mfma<1><<<dim3(E3 / GBN, TB / GBM), dim3(256), 0, stream>>>(
      xb, inwb, in_b, qkvb, TB, E3, EE);

  gemm_bf16_mfma<1><<<dim3(EE / GBN, 2048 / GBM), dim3(256), 0, stream>>>(
      posb, poswb, pos_b, pb, 2048, EE, EE);

  rel_attn_mfma2<<<dim3(TT / QB, BB * HH), dim3(128), 0, stream>>>(
      qkvb, pb, r_w, r_r, ctxb);

  gemm_bf16_mfma<0><<<dim3(EE / GBN, TB / GBM), dim3(256), 0, stream>>>(
      ctxb, outwb, out_b, out, TB, EE, EE);
}